// Round 6
// baseline (345.922 us; speedup 1.0000x reference)
//
#include <hip/hip_runtime.h>

typedef __bf16 bf16x8 __attribute__((ext_vector_type(8)));
typedef float f32x4 __attribute__((ext_vector_type(4)));
typedef unsigned int u32x4 __attribute__((ext_vector_type(4)));
typedef unsigned int u32x2 __attribute__((ext_vector_type(2)));
typedef unsigned short u16x8 __attribute__((ext_vector_type(8)));

#define MFMA_BF16(a, b, c) __builtin_amdgcn_mfma_f32_16x16x32_bf16((a), (b), (c), 0, 0, 0)

// 0.125 (1/sqrt(64)) * log2(e): folded into Q so softmax uses raw exp2
#define QSCALE 0.18033688011112043f

__device__ __forceinline__ unsigned short f2bf(float f) {
    unsigned int u = __builtin_bit_cast(unsigned int, f);
    u += 0x7FFFu + ((u >> 16) & 1u);
    return (unsigned short)(u >> 16);
}

// manual RNE pack — numerically sensitive paths (V) must stay RNE
__device__ __forceinline__ unsigned int pack_bf16_rne(float a, float b) {
    unsigned int ua = __builtin_bit_cast(unsigned int, a);
    unsigned int ub = __builtin_bit_cast(unsigned int, b);
    ua += 0x7FFFu + ((ua >> 16) & 1u);
    ub += 0x7FFFu + ((ub >> 16) & 1u);
    return __builtin_amdgcn_perm(ub, ua, 0x07060302);
}

// cheap pack for P (values in [0,1], self-normalizing) — validated R2-R5
#if __has_builtin(__builtin_amdgcn_cvt_pk_bf16_f32)
typedef __bf16 bf16x2 __attribute__((ext_vector_type(2)));
__device__ __forceinline__ unsigned int pack_bf16(float a, float b) {
    return __builtin_bit_cast(unsigned int, __builtin_amdgcn_cvt_pk_bf16_f32(a, b));
}
#else
__device__ __forceinline__ unsigned int pack_bf16(float a, float b) {
    return pack_bf16_rne(a, b);
}
#endif

// single-instruction exp2: builtin if available, else raw v_exp_f32 (never ocml)
#if __has_builtin(__builtin_amdgcn_exp2f)
__device__ __forceinline__ float fast_exp2(float x) { return __builtin_amdgcn_exp2f(x); }
#else
__device__ __forceinline__ float fast_exp2(float x) {
    float r;
    asm("v_exp_f32 %0, %1\n\ts_nop 0" : "=v"(r) : "v"(x));
    return r;
}
#endif

__device__ __forceinline__ bf16x8 ldfrag(const unsigned short* p) {
    return __builtin_bit_cast(bf16x8, *(const u32x4*)p);
}

// async global->LDS, 16B per lane (GEMMs only)
typedef const __attribute__((address_space(1))) void* gas_t;
typedef __attribute__((address_space(3))) void* las_t;
__device__ __forceinline__ void dma16(const unsigned short* g, unsigned short* l) {
    __builtin_amdgcn_global_load_lds((gas_t)(const void*)g, (las_t)(void*)l, 16, 0, 0);
}

__device__ __forceinline__ void pipeline_barrier() {
    __builtin_amdgcn_s_waitcnt(0);
    __syncthreads();
}

// ---------------- conversion kernels ----------------

__global__ void cvt_x_kernel(const float* __restrict__ in, unsigned short* __restrict__ out) {
    long long t = (long long)blockIdx.x * 256 + threadIdx.x;
    const f32x4* p = (const f32x4*)in + t * 2;
    f32x4 v0 = p[0], v1 = p[1];
    u16x8 o;
    o[0] = f2bf(v0[0]); o[1] = f2bf(v0[1]); o[2] = f2bf(v0[2]); o[3] = f2bf(v0[3]);
    o[4] = f2bf(v1[0]); o[5] = f2bf(v1[1]); o[6] = f2bf(v1[2]); o[7] = f2bf(v1[3]);
    *((u16x8*)out + t) = o;
}

__global__ void cvt_wqkvT_kernel(const float* __restrict__ Wq, const float* __restrict__ Wk,
                                 const float* __restrict__ Wv, unsigned short* __restrict__ WT) {
    int n = blockIdx.x * 256 + threadIdx.x;
    int d0 = blockIdx.y * 8;
    int proj = n >> 10, rem = n & 1023, h = rem >> 6, e = rem & 63;
    const float* W = (proj == 0) ? Wq : (proj == 1) ? Wk : Wv;
    const float* src = W + (size_t)h * 65536 + (size_t)d0 * 64 + e;
    u16x8 o;
#pragma unroll
    for (int j = 0; j < 8; j++) o[j] = f2bf(src[j * 64]);
    *(u16x8*)(WT + (size_t)n * 1024 + d0) = o;
}

__global__ void cvt_woT_kernel(const float* __restrict__ Wo, unsigned short* __restrict__ WoT) {
    int n = blockIdx.x * 256 + threadIdx.x;
    int d0 = blockIdx.y * 8;
    const float* src = Wo + (size_t)d0 * 1024 + n;
    u16x8 o;
#pragma unroll
    for (int j = 0; j < 8; j++) o[j] = f2bf(src[j * 1024]);
    *(u16x8*)(WoT + (size_t)n * 1024 + d0) = o;
}

// ---------------- GEMM kernels: single-barrier double-buffered DMA pipeline ----------------
// LDS: [2][128][32] u16 per operand; LDS(r,c-chunk) = global(r, c ^ (r&3)); frag chunk = quad ^ (lr&3).

__global__ __launch_bounds__(256) void gemm_qkv_kernel(
    const unsigned short* __restrict__ A, const unsigned short* __restrict__ BT,
    const float* __restrict__ bq, const float* __restrict__ bk, const float* __restrict__ bv,
    unsigned short* __restrict__ Qo, unsigned short* __restrict__ Ko, unsigned short* __restrict__ VTo) {
    __shared__ unsigned short As[2 * 128 * 32];
    __shared__ unsigned short Bs[2 * 128 * 32];
    const int tid = threadIdx.x;
    const int m0 = blockIdx.y * 128, n0 = blockIdx.x * 128;
    const int w = tid >> 6, lane = tid & 63, lr = lane & 15, quad = lane >> 4;
    const int wy = w >> 1, wx = w & 1;
    f32x4 acc[4][4];
#pragma unroll
    for (int i = 0; i < 4; i++)
#pragma unroll
        for (int j = 0; j < 4; j++) acc[i][j] = (f32x4){0.f, 0.f, 0.f, 0.f};
    const int drow = lane >> 2;
    const int dchunk = (lane & 3) ^ (drow & 3);
    const unsigned short* gA = A + (size_t)(m0 + w * 32 + drow) * 1024 + dchunk * 8;
    const unsigned short* gB = BT + (size_t)(n0 + w * 32 + drow) * 1024 + dchunk * 8;
    const int swav = (w * 32) * 32;
    const int fcol = (quad ^ (lr & 3)) * 8;
    // prologue: tile 0 -> buf 0
    dma16(gA, As + swav);
    dma16(gA + 16 * 1024, As + swav + 16 * 32);
    dma16(gB, Bs + swav);
    dma16(gB + 16 * 1024, Bs + swav + 16 * 32);
#pragma unroll 2
    for (int k0 = 0; k0 < 1024; k0 += 32) {
        const int cur = (k0 >> 5) & 1;
        const unsigned short* cA = As + cur * 4096;
        const unsigned short* cB = Bs + cur * 4096;
        pipeline_barrier();  // drains this wave's DMA for tile k0; releases buf[cur^1]
        bf16x8 af[4], bfr[4];
#pragma unroll
        for (int i = 0; i < 4; i++) af[i] = ldfrag(cA + (wy * 64 + i * 16 + lr) * 32 + fcol);
#pragma unroll
        for (int j = 0; j < 4; j++) bfr[j] = ldfrag(cB + (wx * 64 + j * 16 + lr) * 32 + fcol);
        if (k0 + 32 < 1024) {  // prefetch tile k0+32 into other buffer
            const int nb = (cur ^ 1) * 4096 + swav;
            dma16(gA + k0 + 32, As + nb);
            dma16(gA + k0 + 32 + 16 * 1024, As + nb + 16 * 32);
            dma16(gB + k0 + 32, Bs + nb);
            dma16(gB + k0 + 32 + 16 * 1024, Bs + nb + 16 * 32);
        }
#pragma unroll
        for (int i = 0; i < 4; i++)
#pragma unroll
            for (int j = 0; j < 4; j++) acc[i][j] = MFMA_BF16(af[i], bfr[j], acc[i][j]);
    }
#pragma unroll
    for (int j = 0; j < 4; j++) {
        int n = n0 + wx * 64 + j * 16 + lr;
        int proj = n >> 10, rem = n & 1023, h = rem >> 6, e = rem & 63;
        if (proj == 2) {
            // V: write transposed [bh, e, s] with packed b64 stores down s (RNE pack!)
            float bb = bv[rem];
#pragma unroll
            for (int i = 0; i < 4; i++) {
                int m = m0 + wy * 64 + i * 16 + quad * 4;
                int batch = m >> 11, s = m & 2047;
                u32x2 pk;
                pk[0] = pack_bf16_rne(acc[i][j][0] + bb, acc[i][j][1] + bb);
                pk[1] = pack_bf16_rne(acc[i][j][2] + bb, acc[i][j][3] + bb);
                *(u32x2*)(VTo + (((size_t)batch * 16 + h) * 64 + e) * 2048 + s) = pk;
            }
        } else {
            const float* bias = (proj == 0) ? bq : bk;
            unsigned short* dst = (proj == 0) ? Qo : Ko;
            float bb = bias[rem];
            float scl = (proj == 0) ? QSCALE : 1.0f;
#pragma unroll
            for (int i = 0; i < 4; i++) {
#pragma unroll
                for (int r = 0; r < 4; r++) {
                    int m = m0 + wy * 64 + i * 16 + quad * 4 + r;
                    int batch = m >> 11, s = m & 2047;
                    dst[(((size_t)batch * 16 + h) * 2048 + s) * 64 + e] = f2bf((acc[i][j][r] + bb) * scl);
                }
            }
        }
    }
}

__global__ __launch_bounds__(256) void gemm_out_kernel(
    const unsigned short* __restrict__ A, const unsigned short* __restrict__ BT,
    const float* __restrict__ bo, float* __restrict__ out) {
    __shared__ unsigned short As[2 * 128 * 32];
    __shared__ unsigned short Bs[2 * 128 * 32];
    const int tid = threadIdx.x;
    const int m0 = blockIdx.y * 128, n0 = blockIdx.x * 128;
    const int w = tid >> 6, lane = tid & 63, lr = lane & 15, quad = lane >> 4;
    const int wy = w >> 1, wx = w & 1;
    f32x4 acc[4][4];
#pragma unroll
    for (int i = 0; i < 4; i++)
#pragma unroll
        for (int j = 0; j < 4; j++) acc[i][j] = (f32x4){0.f, 0.f, 0.f, 0.f};
    const int drow = lane >> 2;
    const int dchunk = (lane & 3) ^ (drow & 3);
    const unsigned short* gA = A + (size_t)(m0 + w * 32 + drow) * 1024 + dchunk * 8;
    const unsigned short* gB = BT + (size_t)(n0 + w * 32 + drow) * 1024 + dchunk * 8;
    const int swav = (w * 32) * 32;
    const int fcol = (quad ^ (lr & 3)) * 8;
    dma16(gA, As + swav);
    dma16(gA + 16 * 1024, As + swav + 16 * 32);
    dma16(gB, Bs + swav);
    dma16(gB + 16 * 1024, Bs + swav + 16 * 32);
#pragma unroll 2
    for (int k0 = 0; k0 < 1024; k0 += 32) {
        const int cur = (k0 >> 5) & 1;
        const unsigned short* cA = As + cur * 4096;
        const unsigned short* cB = Bs + cur * 4096;
        pipeline_barrier();
        bf16x8 af[4], bfr[4];
#pragma unroll
        for (int i = 0; i < 4; i++) af[i] = ldfrag(cA + (wy * 64 + i * 16 + lr) * 32 + fcol);
#pragma unroll
        for (int j = 0; j < 4; j++) bfr[j] = ldfrag(cB + (wx * 64 + j * 16 + lr) * 32 + fcol);
        if (k0 + 32 < 1024) {
            const int nb = (cur ^ 1) * 4096 + swav;
            dma16(gA + k0 + 32, As + nb);
            dma16(gA + k0 + 32 + 16 * 1024, As + nb + 16 * 32);
            dma16(gB + k0 + 32, Bs + nb);
            dma16(gB + k0 + 32 + 16 * 1024, Bs + nb + 16 * 32);
        }
#pragma unroll
        for (int i = 0; i < 4; i++)
#pragma unroll
            for (int j = 0; j < 4; j++) acc[i][j] = MFMA_BF16(af[i], bfr[j], acc[i][j]);
    }
#pragma unroll
    for (int j = 0; j < 4; j++) {
        int n = n0 + wx * 64 + j * 16 + lr;
        float bb = bo[n];
#pragma unroll
        for (int i = 0; i < 4; i++) {
#pragma unroll
            for (int r = 0; r < 4; r++) {
                int m = m0 + wy * 64 + i * 16 + quad * 4 + r;
                out[(size_t)m * 1024 + n] = acc[i][j][r] + bb;
            }
        }
    }
}

// ---------------- flash attention: barrier-free, direct-global K/V fragments ----------------
// Each wave owns 64 q-rows. K/V MFMA fragments load straight from global (L2-resident,
// 64B-segment coalesced) — no K/V LDS staging, no DMA, no __syncthreads anywhere.
// LDS holds only wave-private Q-staging / P rows (stride 72, b128-aligned).
#define ST 72
__global__ __launch_bounds__(256, 2) void attn_fa_kernel(
    const unsigned short* __restrict__ Q, const unsigned short* __restrict__ K,
    const unsigned short* __restrict__ VT, unsigned short* __restrict__ Out) {
    __shared__ unsigned short Ps[256 * ST];  // 36,864 B; rows W..W+63 private to wave w
    const int bh = blockIdx.x;               // bh fastest => same-bh q-tiles share an XCD L2
    const int q0 = blockIdx.y * 256;
    const int tid = threadIdx.x;
    const int w = tid >> 6, lane = tid & 63, lr = lane & 15, quad = lane >> 4;
    const int W = w * 64;
    const unsigned short* Qh = Q + (size_t)bh * 2048 * 64;
    const unsigned short* Kh = K + (size_t)bh * 2048 * 64;
    const unsigned short* Vh = VT + (size_t)bh * 64 * 2048;

    {  // stage this wave's 64 Q rows into Ps (wave-private; lane = row)
        const unsigned short* g = Qh + (size_t)(q0 + W + lane) * 64;
        unsigned short* s = Ps + (W + lane) * ST;
#pragma unroll
        for (int c = 0; c < 8; c++) *(u32x4*)(s + c * 8) = *(const u32x4*)(g + c * 8);
    }
    bf16x8 qb[4][2];  // [q-16-group][kc]
#pragma unroll
    for (int nt = 0; nt < 4; nt++)
#pragma unroll
        for (int kc = 0; kc < 2; kc++)
            qb[nt][kc] = ldfrag(Ps + (W + nt * 16 + lr) * ST + kc * 32 + quad * 8);

    f32x4 o[4][4];  // O[q-16-group][e-16-group]
#pragma unroll
    for (int i = 0; i < 4; i++)
#pragma unroll
        for (int j = 0; j < 4; j++) o[i][j] = (f32x4){0.f, 0.f, 0.f, 0.f};
    float lp[4] = {0.f, 0.f, 0.f, 0.f};

    // per-lane global fragment bases
    const unsigned short* gK = Kh + (size_t)lr * 64 + quad * 8;       // + (t0+mt*16)*64 + kc*32
    const unsigned short* gV = Vh + (size_t)lr * 2048 + quad * 8;     // + et*16*2048 + t0 + kc*32

    for (int t0 = 0; t0 < 2048; t0 += 64) {
        // K fragments direct from global (A-operand of S^T = K·Q^T)
        bf16x8 ka[2][4];
#pragma unroll
        for (int kc = 0; kc < 2; kc++)
#pragma unroll
            for (int mt = 0; mt < 4; mt++)
                ka[kc][mt] = ldfrag(gK + (size_t)(t0 + mt * 16) * 64 + kc * 32);

        f32x4 sc[4][4];  // S^T rows = t (mt), cols = q (nt)
#pragma unroll
        for (int mt = 0; mt < 4; mt++)
#pragma unroll
            for (int nt = 0; nt < 4; nt++) sc[mt][nt] = (f32x4){0.f, 0.f, 0.f, 0.f};
#pragma unroll
        for (int kc = 0; kc < 2; kc++)
#pragma unroll
            for (int mt = 0; mt < 4; mt++)
#pragma unroll
                for (int nt = 0; nt < 4; nt++)
                    sc[mt][nt] = MFMA_BF16(ka[kc][mt], qb[nt][kc], sc[mt][nt]);

        // V^T fragments (issued before softmax so L2 latency overlaps the VALU phase)
        bf16x8 vb[2][4];
#pragma unroll
        for (int kc = 0; kc < 2; kc++)
#pragma unroll
            for (int et = 0; et < 4; et++)
                vb[kc][et] = ldfrag(gV + (size_t)(et * 16) * 2048 + t0 + kc * 32);

        // p = exp2(s'); accumulate denominator; pack to bf16 rows of P[q][t]
#pragma unroll
        for (int nt = 0; nt < 4; nt++) {
            unsigned short* prow = Ps + (W + nt * 16 + lr) * ST + quad * 4;
#pragma unroll
            for (int mt = 0; mt < 4; mt++) {
                float p0 = fast_exp2(sc[mt][nt][0]);
                float p1 = fast_exp2(sc[mt][nt][1]);
                float p2 = fast_exp2(sc[mt][nt][2]);
                float p3 = fast_exp2(sc[mt][nt][3]);
                lp[nt] += (p0 + p1) + (p2 + p3);
                u32x2 pk;
                pk[0] = pack_bf16(p0, p1);
                pk[1] = pack_bf16(p2, p3);
                *(u32x2*)(prow + mt * 16) = pk;
            }
        }

        // O += P·V  (pa from own-wave LDS rows; lgkm ordering within wave suffices)
#pragma unroll
        for (int kc = 0; kc < 2; kc++) {
            bf16x8 pa[4];
#pragma unroll
            for (int nt = 0; nt < 4; nt++)
                pa[nt] = ldfrag(Ps + (W + nt * 16 + lr) * ST + kc * 32 + quad * 8);
#pragma unroll
            for (int nt = 0; nt < 4; nt++)
#pragma unroll
                for (int et = 0; et < 4; et++)
                    o[nt][et] = MFMA_BF16(pa[nt], vb[kc][et], o[nt][et]);
        }
    }

    // final denominator: reduce across the 4 quads
#pragma unroll
    for (int nt = 0; nt < 4; nt++) {
        float l = lp[nt];
        l += __shfl_xor(l, 16, 64);
        l += __shfl_xor(l, 32, 64);
        lp[nt] = l;
    }

    // normalize + write attn [B,S,H*E] bf16
    const int h = bh & 15, b = bh >> 4;
#pragma unroll
    for (int nt = 0; nt < 4; nt++) {
#pragma unroll
        for (int r = 0; r < 4; r++) {
            float l = __shfl(lp[nt], quad * 4 + r, 16);
            float inv = 1.0f / l;
            int s = q0 + W + nt * 16 + quad * 4 + r;
#pragma unroll
            for (int et = 0; et < 4; et++) {
                int col = h * 64 + et * 16 + lr;
                Out[((size_t)(b * 2048 + s)) * 1024 + col] = f2bf(o[nt][et][r] * inv);
            }
        }
    }
}

// ---------------- launch ----------------

extern "C" void kernel_launch(void* const* d_in, const int* in_sizes, int n_in,
                              void* d_out, int out_size, void* d_ws, size_t ws_size,
                              hipStream_t stream) {
    const float* x  = (const float*)d_in[0];
    const float* Wq = (const float*)d_in[1];
    const float* bq = (const float*)d_in[2];
    const float* Wk = (const float*)d_in[3];
    const float* bk = (const float*)d_in[4];
    const float* Wv = (const float*)d_in[5];
    const float* bv = (const float*)d_in[6];
    const float* Wo = (const float*)d_in[7];
    const float* bo = (const float*)d_in[8];
    float* out = (float*)d_out;

    char* ws = (char*)d_ws;
    unsigned short* xb    = (unsigned short*)(ws);              // 16 MiB; reused as attn buffer
    unsigned short* WqkvT = (unsigned short*)(ws + 16777216);   // 6 MiB
    unsigned short* WoT   = (unsigned short*)(ws + 23068672);   // 2 MiB
    unsigned short* Qb    = (unsigned short*)(ws + 25165824);   // 16 MiB
    unsigned short* Kb    = (unsigned short*)(ws + 41943040);   // 16 MiB
    unsigned short* VTb   = (unsigned short*)(ws + 58720256);   // 16 MiB (total 72 MiB)
    unsigned short* attn  = xb;  // xb is dead after gemm_qkv

    cvt_x_kernel<<<dim3(4096), dim3(256), 0, stream>>>(x, xb);
    cvt_wqkvT_kernel<<<dim3(12, 128), dim3(256), 0, stream>>>(Wq, Wk, Wv, WqkvT);
    cvt_woT_kernel<<<dim3(4, 128), dim3(256), 0, stream>>>(Wo, WoT);
    gemm_qkv_kernel<<<dim3(24, 64), dim3(256), 0, stream>>>(xb, WqkvT, bq, bk, bv, Qb, Kb, VTb);
    attn_fa_kernel<<<dim3(64, 8), dim3(256), 0, stream>>>(Qb, Kb, VTb, attn);
    gemm_out_kernel<<<dim3(8, 64), dim3(256), 0, stream>>>(attn, WoT, bo, out);
}

// Round 7
// 307.413 us; speedup vs baseline: 1.1253x; 1.1253x over previous
//
#include <hip/hip_runtime.h>

typedef __bf16 bf16x8 __attribute__((ext_vector_type(8)));
typedef float f32x4 __attribute__((ext_vector_type(4)));
typedef unsigned int u32x4 __attribute__((ext_vector_type(4)));
typedef unsigned int u32x2 __attribute__((ext_vector_type(2)));
typedef unsigned short u16x8 __attribute__((ext_vector_type(8)));

#define MFMA_BF16(a, b, c) __builtin_amdgcn_mfma_f32_16x16x32_bf16((a), (b), (c), 0, 0, 0)

// 0.125 (1/sqrt(64)) * log2(e): folded into Q so softmax uses raw exp2
#define QSCALE 0.18033688011112043f

__device__ __forceinline__ unsigned short f2bf(float f) {
    unsigned int u = __builtin_bit_cast(unsigned int, f);
    u += 0x7FFFu + ((u >> 16) & 1u);
    return (unsigned short)(u >> 16);
}

// manual RNE pack — numerically sensitive paths (V) must stay RNE
__device__ __forceinline__ unsigned int pack_bf16_rne(float a, float b) {
    unsigned int ua = __builtin_bit_cast(unsigned int, a);
    unsigned int ub = __builtin_bit_cast(unsigned int, b);
    ua += 0x7FFFu + ((ua >> 16) & 1u);
    ub += 0x7FFFu + ((ub >> 16) & 1u);
    return __builtin_amdgcn_perm(ub, ua, 0x07060302);
}

// cheap pack for P (values in [0,1], self-normalizing) — validated R2-R5
#if __has_builtin(__builtin_amdgcn_cvt_pk_bf16_f32)
typedef __bf16 bf16x2 __attribute__((ext_vector_type(2)));
__device__ __forceinline__ unsigned int pack_bf16(float a, float b) {
    return __builtin_bit_cast(unsigned int, __builtin_amdgcn_cvt_pk_bf16_f32(a, b));
}
#else
__device__ __forceinline__ unsigned int pack_bf16(float a, float b) {
    return pack_bf16_rne(a, b);
}
#endif

// single-instruction exp2: builtin if available, else raw v_exp_f32 (never ocml)
#if __has_builtin(__builtin_amdgcn_exp2f)
__device__ __forceinline__ float fast_exp2(float x) { return __builtin_amdgcn_exp2f(x); }
#else
__device__ __forceinline__ float fast_exp2(float x) {
    float r;
    asm("v_exp_f32 %0, %1\n\ts_nop 0" : "=v"(r) : "v"(x));
    return r;
}
#endif

__device__ __forceinline__ bf16x8 ldfrag(const unsigned short* p) {
    return __builtin_bit_cast(bf16x8, *(const u32x4*)p);
}

// async global->LDS, 16B per lane; LDS dst = wave-uniform base + lane*16B
typedef const __attribute__((address_space(1))) void* gas_t;
typedef __attribute__((address_space(3))) void* las_t;
__device__ __forceinline__ void dma16(const unsigned short* g, unsigned short* l) {
    __builtin_amdgcn_global_load_lds((gas_t)(const void*)g, (las_t)(void*)l, 16, 0, 0);
}

// drain this wave's outstanding DMA/LDS ops, then block barrier (dbuf visibility)
__device__ __forceinline__ void pipeline_barrier() {
    __builtin_amdgcn_s_waitcnt(0);
    __syncthreads();
}

// ---------------- conversion kernels ----------------

__global__ void cvt_x_kernel(const float* __restrict__ in, unsigned short* __restrict__ out) {
    long long t = (long long)blockIdx.x * 256 + threadIdx.x;
    const f32x4* p = (const f32x4*)in + t * 2;
    f32x4 v0 = p[0], v1 = p[1];
    u16x8 o;
    o[0] = f2bf(v0[0]); o[1] = f2bf(v0[1]); o[2] = f2bf(v0[2]); o[3] = f2bf(v0[3]);
    o[4] = f2bf(v1[0]); o[5] = f2bf(v1[1]); o[6] = f2bf(v1[2]); o[7] = f2bf(v1[3]);
    *((u16x8*)out + t) = o;
}

__global__ void cvt_wqkvT_kernel(const float* __restrict__ Wq, const float* __restrict__ Wk,
                                 const float* __restrict__ Wv, unsigned short* __restrict__ WT) {
    int n = blockIdx.x * 256 + threadIdx.x;
    int d0 = blockIdx.y * 8;
    int proj = n >> 10, rem = n & 1023, h = rem >> 6, e = rem & 63;
    const float* W = (proj == 0) ? Wq : (proj == 1) ? Wk : Wv;
    const float* src = W + (size_t)h * 65536 + (size_t)d0 * 64 + e;
    u16x8 o;
#pragma unroll
    for (int j = 0; j < 8; j++) o[j] = f2bf(src[j * 64]);
    *(u16x8*)(WT + (size_t)n * 1024 + d0) = o;
}

__global__ void cvt_woT_kernel(const float* __restrict__ Wo, unsigned short* __restrict__ WoT) {
    int n = blockIdx.x * 256 + threadIdx.x;
    int d0 = blockIdx.y * 8;
    const float* src = Wo + (size_t)d0 * 1024 + n;
    u16x8 o;
#pragma unroll
    for (int j = 0; j < 8; j++) o[j] = f2bf(src[j * 1024]);
    *(u16x8*)(WoT + (size_t)n * 1024 + d0) = o;
}

// ---------------- GEMM kernels: single-barrier double-buffered DMA pipeline ----------------
// LDS: [2][128][32] u16 per operand; LDS(r,c-chunk) = global(r, c ^ (r&3)); frag chunk = quad ^ (lr&3).

__global__ __launch_bounds__(256) void gemm_qkv_kernel(
    const unsigned short* __restrict__ A, const unsigned short* __restrict__ BT,
    const float* __restrict__ bq, const float* __restrict__ bk, const float* __restrict__ bv,
    unsigned short* __restrict__ Qo, unsigned short* __restrict__ Ko, unsigned short* __restrict__ VTo) {
    __shared__ unsigned short As[2 * 128 * 32];
    __shared__ unsigned short Bs[2 * 128 * 32];
    const int tid = threadIdx.x;
    const int m0 = blockIdx.y * 128, n0 = blockIdx.x * 128;
    const int w = tid >> 6, lane = tid & 63, lr = lane & 15, quad = lane >> 4;
    const int wy = w >> 1, wx = w & 1;
    f32x4 acc[4][4];
#pragma unroll
    for (int i = 0; i < 4; i++)
#pragma unroll
        for (int j = 0; j < 4; j++) acc[i][j] = (f32x4){0.f, 0.f, 0.f, 0.f};
    const int drow = lane >> 2;
    const int dchunk = (lane & 3) ^ (drow & 3);
    const unsigned short* gA = A + (size_t)(m0 + w * 32 + drow) * 1024 + dchunk * 8;
    const unsigned short* gB = BT + (size_t)(n0 + w * 32 + drow) * 1024 + dchunk * 8;
    const int swav = (w * 32) * 32;
    const int fcol = (quad ^ (lr & 3)) * 8;
    // prologue: tile 0 -> buf 0
    dma16(gA, As + swav);
    dma16(gA + 16 * 1024, As + swav + 16 * 32);
    dma16(gB, Bs + swav);
    dma16(gB + 16 * 1024, Bs + swav + 16 * 32);
#pragma unroll 2
    for (int k0 = 0; k0 < 1024; k0 += 32) {
        const int cur = (k0 >> 5) & 1;
        const unsigned short* cA = As + cur * 4096;
        const unsigned short* cB = Bs + cur * 4096;
        pipeline_barrier();  // drains this wave's DMA for tile k0; releases buf[cur^1]
        bf16x8 af[4], bfr[4];
#pragma unroll
        for (int i = 0; i < 4; i++) af[i] = ldfrag(cA + (wy * 64 + i * 16 + lr) * 32 + fcol);
#pragma unroll
        for (int j = 0; j < 4; j++) bfr[j] = ldfrag(cB + (wx * 64 + j * 16 + lr) * 32 + fcol);
        if (k0 + 32 < 1024) {  // prefetch tile k0+32 into other buffer
            const int nb = (cur ^ 1) * 4096 + swav;
            dma16(gA + k0 + 32, As + nb);
            dma16(gA + k0 + 32 + 16 * 1024, As + nb + 16 * 32);
            dma16(gB + k0 + 32, Bs + nb);
            dma16(gB + k0 + 32 + 16 * 1024, Bs + nb + 16 * 32);
        }
#pragma unroll
        for (int i = 0; i < 4; i++)
#pragma unroll
            for (int j = 0; j < 4; j++) acc[i][j] = MFMA_BF16(af[i], bfr[j], acc[i][j]);
    }
#pragma unroll
    for (int j = 0; j < 4; j++) {
        int n = n0 + wx * 64 + j * 16 + lr;
        int proj = n >> 10, rem = n & 1023, h = rem >> 6, e = rem & 63;
        if (proj == 2) {
            // V: write transposed [bh, e, s] with packed b64 stores down s (RNE pack!)
            float bb = bv[rem];
#pragma unroll
            for (int i = 0; i < 4; i++) {
                int m = m0 + wy * 64 + i * 16 + quad * 4;
                int batch = m >> 11, s = m & 2047;
                u32x2 pk;
                pk[0] = pack_bf16_rne(acc[i][j][0] + bb, acc[i][j][1] + bb);
                pk[1] = pack_bf16_rne(acc[i][j][2] + bb, acc[i][j][3] + bb);
                *(u32x2*)(VTo + (((size_t)batch * 16 + h) * 64 + e) * 2048 + s) = pk;
            }
        } else {
            const float* bias = (proj == 0) ? bq : bk;
            unsigned short* dst = (proj == 0) ? Qo : Ko;
            float bb = bias[rem];
            float scl = (proj == 0) ? QSCALE : 1.0f;
#pragma unroll
            for (int i = 0; i < 4; i++) {
#pragma unroll
                for (int r = 0; r < 4; r++) {
                    int m = m0 + wy * 64 + i * 16 + quad * 4 + r;
                    int batch = m >> 11, s = m & 2047;
                    dst[(((size_t)batch * 16 + h) * 2048 + s) * 64 + e] = f2bf((acc[i][j][r] + bb) * scl);
                }
            }
        }
    }
}

__global__ __launch_bounds__(256) void gemm_out_kernel(
    const unsigned short* __restrict__ A, const unsigned short* __restrict__ BT,
    const float* __restrict__ bo, float* __restrict__ out) {
    __shared__ unsigned short As[2 * 128 * 32];
    __shared__ unsigned short Bs[2 * 128 * 32];
    const int tid = threadIdx.x;
    const int m0 = blockIdx.y * 128, n0 = blockIdx.x * 128;
    const int w = tid >> 6, lane = tid & 63, lr = lane & 15, quad = lane >> 4;
    const int wy = w >> 1, wx = w & 1;
    f32x4 acc[4][4];
#pragma unroll
    for (int i = 0; i < 4; i++)
#pragma unroll
        for (int j = 0; j < 4; j++) acc[i][j] = (f32x4){0.f, 0.f, 0.f, 0.f};
    const int drow = lane >> 2;
    const int dchunk = (lane & 3) ^ (drow & 3);
    const unsigned short* gA = A + (size_t)(m0 + w * 32 + drow) * 1024 + dchunk * 8;
    const unsigned short* gB = BT + (size_t)(n0 + w * 32 + drow) * 1024 + dchunk * 8;
    const int swav = (w * 32) * 32;
    const int fcol = (quad ^ (lr & 3)) * 8;
    dma16(gA, As + swav);
    dma16(gA + 16 * 1024, As + swav + 16 * 32);
    dma16(gB, Bs + swav);
    dma16(gB + 16 * 1024, Bs + swav + 16 * 32);
#pragma unroll 2
    for (int k0 = 0; k0 < 1024; k0 += 32) {
        const int cur = (k0 >> 5) & 1;
        const unsigned short* cA = As + cur * 4096;
        const unsigned short* cB = Bs + cur * 4096;
        pipeline_barrier();
        bf16x8 af[4], bfr[4];
#pragma unroll
        for (int i = 0; i < 4; i++) af[i] = ldfrag(cA + (wy * 64 + i * 16 + lr) * 32 + fcol);
#pragma unroll
        for (int j = 0; j < 4; j++) bfr[j] = ldfrag(cB + (wx * 64 + j * 16 + lr) * 32 + fcol);
        if (k0 + 32 < 1024) {
            const int nb = (cur ^ 1) * 4096 + swav;
            dma16(gA + k0 + 32, As + nb);
            dma16(gA + k0 + 32 + 16 * 1024, As + nb + 16 * 32);
            dma16(gB + k0 + 32, Bs + nb);
            dma16(gB + k0 + 32 + 16 * 1024, Bs + nb + 16 * 32);
        }
#pragma unroll
        for (int i = 0; i < 4; i++)
#pragma unroll
            for (int j = 0; j < 4; j++) acc[i][j] = MFMA_BF16(af[i], bfr[j], acc[i][j]);
    }
#pragma unroll
    for (int j = 0; j < 4; j++) {
        int n = n0 + wx * 64 + j * 16 + lr;
        float bb = bo[n];
#pragma unroll
        for (int i = 0; i < 4; i++) {
#pragma unroll
            for (int r = 0; r < 4; r++) {
                int m = m0 + wy * 64 + i * 16 + quad * 4 + r;
                out[(size_t)m * 1024 + n] = acc[i][j][r] + bb;
            }
        }
    }
}

// ---------------- flash attention: hybrid (R5 LDS-staged dbuf K/V + 64 q-rows/wave) ----------------
// grid (bh=64 fastest -> all 8 q-tiles of a bh share one XCD's L2, 512 blocks = 2/CU exact).
// K/V tiles: [2][64][64] u16, source-swizzled LDS(r,c)=global(r, c^(r&7));
// frag reads use chunk (kc*4+quad)^(lr&7) -> <=2-way (free) b128.
// Ps: 256 rows x 72 (wave-private rows) for Q staging + P round-trip.
#define ST 72
__global__ __launch_bounds__(256, 2) void attn_fa_kernel(
    const unsigned short* __restrict__ Q, const unsigned short* __restrict__ K,
    const unsigned short* __restrict__ VT, unsigned short* __restrict__ Out) {
    __shared__ unsigned short Ks[2 * 64 * 64];
    __shared__ unsigned short Vs[2 * 64 * 64];
    __shared__ unsigned short Ps[256 * ST];  // 36,864 B
    const int bh = blockIdx.x;
    const int q0 = blockIdx.y * 256;
    const int tid = threadIdx.x;
    const int w = tid >> 6, lane = tid & 63, lr = lane & 15, quad = lane >> 4;
    const int W = w * 64;
    const unsigned short* Qh = Q + (size_t)bh * 2048 * 64;
    const unsigned short* Kh = K + (size_t)bh * 2048 * 64;
    const unsigned short* Vh = VT + (size_t)bh * 64 * 2048;

    // DMA setup: wave w stages K/V rows w*16 .. w*16+15 (2 instrs of 8 rows each)
    const int drow = lane >> 3;
    const int dchunk = (lane & 7) ^ drow;
    const unsigned short* gK = Kh + (size_t)(w * 16 + drow) * 64 + dchunk * 8;
    const unsigned short* gV = Vh + (size_t)(w * 16 + drow) * 2048 + dchunk * 8;
    const int swav = (w * 16) * 64;
    // prologue: tile 0 -> buf 0
    dma16(gK, Ks + swav);
    dma16(gK + 8 * 64, Ks + swav + 8 * 64);
    dma16(gV, Vs + swav);
    dma16(gV + 8 * 2048, Vs + swav + 8 * 64);

    {  // stage this wave's 64 Q rows into Ps (lane = row; wave-private rows)
        const unsigned short* g = Qh + (size_t)(q0 + W + lane) * 64;
        unsigned short* s = Ps + (W + lane) * ST;
#pragma unroll
        for (int c = 0; c < 8; c++) *(u32x4*)(s + c * 8) = *(const u32x4*)(g + c * 8);
    }
    bf16x8 qb[4][2];  // [q-16-group][kc]
#pragma unroll
    for (int nt = 0; nt < 4; nt++)
#pragma unroll
        for (int kc = 0; kc < 2; kc++)
            qb[nt][kc] = ldfrag(Ps + (W + nt * 16 + lr) * ST + kc * 32 + quad * 8);

    f32x4 o[4][4];  // O[q-16-group][e-16-group]
#pragma unroll
    for (int i = 0; i < 4; i++)
#pragma unroll
        for (int j = 0; j < 4; j++) o[i][j] = (f32x4){0.f, 0.f, 0.f, 0.f};
    float lp[4] = {0.f, 0.f, 0.f, 0.f};

    for (int t0 = 0; t0 < 2048; t0 += 64) {
        const int cur = (t0 >> 6) & 1;
        const unsigned short* cK = Ks + cur * 4096;
        const unsigned short* cV = Vs + cur * 4096;
        pipeline_barrier();  // drains this tile's DMA; releases other buffer
        // hoist ALL K/V fragment reads before the prefetch DMA issue
        bf16x8 ka[2][4], vb[2][4];
#pragma unroll
        for (int kc = 0; kc < 2; kc++)
#pragma unroll
            for (int mt = 0; mt < 4; mt++) {
                int fc = ((kc * 4 + quad) ^ (lr & 7)) * 8;
                ka[kc][mt] = ldfrag(cK + (mt * 16 + lr) * 64 + fc);
                vb[kc][mt] = ldfrag(cV + (mt * 16 + lr) * 64 + fc);
            }
        if (t0 + 64 < 2048) {  // prefetch next tile into other buffer
            const int nb = (cur ^ 1) * 4096 + swav;
            dma16(gK + (size_t)(t0 + 64) * 64, Ks + nb);
            dma16(gK + (size_t)(t0 + 64) * 64 + 8 * 64, Ks + nb + 8 * 64);
            dma16(gV + t0 + 64, Vs + nb);
            dma16(gV + t0 + 64 + 8 * 2048, Vs + nb + 8 * 64);
        }

        // S^T = K·Q^T : C rows = t (mt), cols = q (nt)
        f32x4 sc[4][4];
#pragma unroll
        for (int mt = 0; mt < 4; mt++)
#pragma unroll
            for (int nt = 0; nt < 4; nt++) sc[mt][nt] = (f32x4){0.f, 0.f, 0.f, 0.f};
#pragma unroll
        for (int kc = 0; kc < 2; kc++)
#pragma unroll
            for (int mt = 0; mt < 4; mt++)
#pragma unroll
                for (int nt = 0; nt < 4; nt++)
                    sc[mt][nt] = MFMA_BF16(ka[kc][mt], qb[nt][kc], sc[mt][nt]);

        // p = exp2(s'); accumulate denominator; pack to bf16 rows of P[q][t]
#pragma unroll
        for (int nt = 0; nt < 4; nt++) {
            unsigned short* prow = Ps + (W + nt * 16 + lr) * ST + quad * 4;
#pragma unroll
            for (int mt = 0; mt < 4; mt++) {
                float p0 = fast_exp2(sc[mt][nt][0]);
                float p1 = fast_exp2(sc[mt][nt][1]);
                float p2 = fast_exp2(sc[mt][nt][2]);
                float p3 = fast_exp2(sc[mt][nt][3]);
                lp[nt] += (p0 + p1) + (p2 + p3);
                u32x2 pk;
                pk[0] = pack_bf16(p0, p1);
                pk[1] = pack_bf16(p2, p3);
                *(u32x2*)(prow + mt * 16) = pk;
            }
        }

        // O += P·V  (pa from own-wave LDS rows; same-wave lgkm ordering suffices)
#pragma unroll
        for (int kc = 0; kc < 2; kc++) {
            bf16x8 pa[4];
#pragma unroll
            for (int nt = 0; nt < 4; nt++)
                pa[nt] = ldfrag(Ps + (W + nt * 16 + lr) * ST + kc * 32 + quad * 8);
#pragma unroll
            for (int nt = 0; nt < 4; nt++)
#pragma unroll
                for (int et = 0; et < 4; et++)
                    o[nt][et] = MFMA_BF16(pa[nt], vb[kc][et], o[nt][et]);
        }
    }

    // final denominator: reduce across the 4 quads
#pragma unroll
    for (int nt = 0; nt < 4; nt++) {
        float l = lp[nt];
        l += __shfl_xor(l, 16, 64);
        l += __shfl_xor(l, 32, 64);
        lp[nt] = l;
    }

    // normalize + write attn [B,S,H*E] bf16
    const int h = bh & 15, b = bh >> 4;
#pragma unroll
    for (int nt = 0; nt < 4; nt++) {
#pragma unroll
        for (int r = 0; r < 4; r++) {
            float l = __shfl(lp[nt], quad * 4 + r, 16);
            float inv = 1.0f / l;
            int s = q0 + W + nt * 16 + quad * 4 + r;
#pragma unroll
            for (int et = 0; et < 4; et++) {
                int col = h * 64 + et * 16 + lr;
                Out[((size_t)(b * 2048 + s)) * 1024 + col] = f2bf(o[nt][et][r] * inv);
            }
        }
    }
}

// ---------------- launch ----------------

extern "C" void kernel_launch(void* const* d_in, const int* in_sizes, int n_in,
                              void* d_out, int out_size, void* d_ws, size_t ws_size,
                              hipStream_t stream) {
    const float* x  = (const float*)d_in[0];
    const float* Wq = (const float*)d_in[1];
    const float* bq = (const float*)d_in[2];
    const float* Wk = (const float*)d_in[3];
    const float* bk = (const float*)d_in[4];
    const float* Wv = (const float*)d_in[5];
    const float* bv = (const float*)d_in[6];
    const float* Wo = (const float*)d_in[7];
    const float* bo = (const float*)d_in[8];
    float* out = (float*)d_out;

    char* ws = (char*)d_ws;
    unsigned short* xb    = (unsigned short*)(ws);              // 16 MiB; reused as attn buffer
    unsigned short* WqkvT = (unsigned short*)(ws + 16777216);   // 6 MiB
    unsigned short* WoT   = (unsigned short*)(ws + 23068672);   // 2 MiB
    unsigned short* Qb    = (unsigned short*)(ws + 25165824);   // 16 MiB
    unsigned short* Kb    = (unsigned short*)(ws + 41943040);   // 16 MiB
    unsigned short* VTb   = (unsigned short*)(ws + 58720256);   // 16 MiB (total 72 MiB)
    unsigned short* attn  = xb;  // xb is dead after gemm_qkv

    cvt_x_kernel<<<dim3(4096), dim3(256), 0, stream>>>(x, xb);
    cvt_wqkvT_kernel<<<dim3(12, 128), dim3(256), 0, stream>>>(Wq, Wk, Wv, WqkvT);
    cvt_woT_kernel<<<dim3(4, 128), dim3(256), 0, stream>>>(Wo, WoT);
    gemm_qkv_kernel<<<dim3(24, 64), dim3(256), 0, stream>>>(xb, WqkvT, bq, bk, bv, Qb, Kb, VTb);
    attn_fa_kernel<<<dim3(64, 8), dim3(256), 0, stream>>>(Qb, Kb, VTb, attn);
    gemm_out_kernel<<<dim3(8, 64), dim3(256), 0, stream>>>(attn, WoT, bo, out);
}

// Round 8
// 300.023 us; speedup vs baseline: 1.1530x; 1.0246x over previous
//
#include <hip/hip_runtime.h>

typedef __bf16 bf16x8 __attribute__((ext_vector_type(8)));
typedef float f32x4 __attribute__((ext_vector_type(4)));
typedef unsigned int u32x4 __attribute__((ext_vector_type(4)));
typedef unsigned int u32x2 __attribute__((ext_vector_type(2)));
typedef unsigned short u16x8 __attribute__((ext_vector_type(8)));

#define MFMA_BF16(a, b, c) __builtin_amdgcn_mfma_f32_16x16x32_bf16((a), (b), (c), 0, 0, 0)

// 0.125 (1/sqrt(64)) * log2(e): folded into Q so softmax uses raw exp2
#define QSCALE 0.18033688011112043f

__device__ __forceinline__ unsigned short f2bf(float f) {
    unsigned int u = __builtin_bit_cast(unsigned int, f);
    u += 0x7FFFu + ((u >> 16) & 1u);
    return (unsigned short)(u >> 16);
}

// manual RNE pack — numerically sensitive paths (V) must stay RNE
__device__ __forceinline__ unsigned int pack_bf16_rne(float a, float b) {
    unsigned int ua = __builtin_bit_cast(unsigned int, a);
    unsigned int ub = __builtin_bit_cast(unsigned int, b);
    ua += 0x7FFFu + ((ua >> 16) & 1u);
    ub += 0x7FFFu + ((ub >> 16) & 1u);
    return __builtin_amdgcn_perm(ub, ua, 0x07060302);
}

// cheap pack for P (values in [0,1], self-normalizing) — validated R2-R7
#if __has_builtin(__builtin_amdgcn_cvt_pk_bf16_f32)
typedef __bf16 bf16x2 __attribute__((ext_vector_type(2)));
__device__ __forceinline__ unsigned int pack_bf16(float a, float b) {
    return __builtin_bit_cast(unsigned int, __builtin_amdgcn_cvt_pk_bf16_f32(a, b));
}
#else
__device__ __forceinline__ unsigned int pack_bf16(float a, float b) {
    return pack_bf16_rne(a, b);
}
#endif

// single-instruction exp2: builtin if available, else raw v_exp_f32 (never ocml)
#if __has_builtin(__builtin_amdgcn_exp2f)
__device__ __forceinline__ float fast_exp2(float x) { return __builtin_amdgcn_exp2f(x); }
#else
__device__ __forceinline__ float fast_exp2(float x) {
    float r;
    asm("v_exp_f32 %0, %1\n\ts_nop 0" : "=v"(r) : "v"(x));
    return r;
}
#endif

__device__ __forceinline__ bf16x8 ldfrag(const unsigned short* p) {
    return __builtin_bit_cast(bf16x8, *(const u32x4*)p);
}

// async global->LDS, 16B per lane; LDS dst = wave-uniform base + lane*16B
typedef const __attribute__((address_space(1))) void* gas_t;
typedef __attribute__((address_space(3))) void* las_t;
__device__ __forceinline__ void dma16(const unsigned short* g, unsigned short* l) {
    __builtin_amdgcn_global_load_lds((gas_t)(const void*)g, (las_t)(void*)l, 16, 0, 0);
}

// drain this wave's outstanding DMA/LDS ops, then block barrier (staging visibility)
__device__ __forceinline__ void pipeline_barrier() {
    __builtin_amdgcn_s_waitcnt(0);
    __syncthreads();
}

// ---------------- conversion kernels ----------------

__global__ void cvt_x_kernel(const float* __restrict__ in, unsigned short* __restrict__ out) {
    long long t = (long long)blockIdx.x * 256 + threadIdx.x;
    const f32x4* p = (const f32x4*)in + t * 2;
    f32x4 v0 = p[0], v1 = p[1];
    u16x8 o;
    o[0] = f2bf(v0[0]); o[1] = f2bf(v0[1]); o[2] = f2bf(v0[2]); o[3] = f2bf(v0[3]);
    o[4] = f2bf(v1[0]); o[5] = f2bf(v1[1]); o[6] = f2bf(v1[2]); o[7] = f2bf(v1[3]);
    *((u16x8*)out + t) = o;
}

__global__ void cvt_wqkvT_kernel(const float* __restrict__ Wq, const float* __restrict__ Wk,
                                 const float* __restrict__ Wv, unsigned short* __restrict__ WT) {
    int n = blockIdx.x * 256 + threadIdx.x;
    int d0 = blockIdx.y * 8;
    int proj = n >> 10, rem = n & 1023, h = rem >> 6, e = rem & 63;
    const float* W = (proj == 0) ? Wq : (proj == 1) ? Wk : Wv;
    const float* src = W + (size_t)h * 65536 + (size_t)d0 * 64 + e;
    u16x8 o;
#pragma unroll
    for (int j = 0; j < 8; j++) o[j] = f2bf(src[j * 64]);
    *(u16x8*)(WT + (size_t)n * 1024 + d0) = o;
}

__global__ void cvt_woT_kernel(const float* __restrict__ Wo, unsigned short* __restrict__ WoT) {
    int n = blockIdx.x * 256 + threadIdx.x;
    int d0 = blockIdx.y * 8;
    const float* src = Wo + (size_t)d0 * 1024 + n;
    u16x8 o;
#pragma unroll
    for (int j = 0; j < 8; j++) o[j] = f2bf(src[j * 1024]);
    *(u16x8*)(WoT + (size_t)n * 1024 + d0) = o;
}

// ---------------- GEMM kernels: single-barrier double-buffered DMA pipeline ----------------
// LDS: [2][128][32] u16 per operand; LDS(r,c-chunk) = global(r, c ^ (r&3)); frag chunk = quad ^ (lr&3).
// NOTE: no "#pragma unroll 2" on the K-loop — R6/R7 showed it regresses (~20 µs, m141-style).

__global__ __launch_bounds__(256) void gemm_qkv_kernel(
    const unsigned short* __restrict__ A, const unsigned short* __restrict__ BT,
    const float* __restrict__ bq, const float* __restrict__ bk, const float* __restrict__ bv,
    unsigned short* __restrict__ Qo, unsigned short* __restrict__ Ko, unsigned short* __restrict__ VTo) {
    __shared__ unsigned short As[2 * 128 * 32];
    __shared__ unsigned short Bs[2 * 128 * 32];
    const int tid = threadIdx.x;
    const int m0 = blockIdx.y * 128, n0 = blockIdx.x * 128;
    const int w = tid >> 6, lane = tid & 63, lr = lane & 15, quad = lane >> 4;
    const int wy = w >> 1, wx = w & 1;
    f32x4 acc[4][4];
#pragma unroll
    for (int i = 0; i < 4; i++)
#pragma unroll
        for (int j = 0; j < 4; j++) acc[i][j] = (f32x4){0.f, 0.f, 0.f, 0.f};
    const int drow = lane >> 2;
    const int dchunk = (lane & 3) ^ (drow & 3);
    const unsigned short* gA = A + (size_t)(m0 + w * 32 + drow) * 1024 + dchunk * 8;
    const unsigned short* gB = BT + (size_t)(n0 + w * 32 + drow) * 1024 + dchunk * 8;
    const int swav = (w * 32) * 32;
    const int fcol = (quad ^ (lr & 3)) * 8;
    // prologue: tile 0 -> buf 0
    dma16(gA, As + swav);
    dma16(gA + 16 * 1024, As + swav + 16 * 32);
    dma16(gB, Bs + swav);
    dma16(gB + 16 * 1024, Bs + swav + 16 * 32);
    for (int k0 = 0; k0 < 1024; k0 += 32) {
        const int cur = (k0 >> 5) & 1;
        const unsigned short* cA = As + cur * 4096;
        const unsigned short* cB = Bs + cur * 4096;
        pipeline_barrier();  // drains this wave's DMA for tile k0; releases buf[cur^1]
        bf16x8 af[4], bfr[4];
#pragma unroll
        for (int i = 0; i < 4; i++) af[i] = ldfrag(cA + (wy * 64 + i * 16 + lr) * 32 + fcol);
#pragma unroll
        for (int j = 0; j < 4; j++) bfr[j] = ldfrag(cB + (wx * 64 + j * 16 + lr) * 32 + fcol);
        if (k0 + 32 < 1024) {  // prefetch tile k0+32 into other buffer
            const int nb = (cur ^ 1) * 4096 + swav;
            dma16(gA + k0 + 32, As + nb);
            dma16(gA + k0 + 32 + 16 * 1024, As + nb + 16 * 32);
            dma16(gB + k0 + 32, Bs + nb);
            dma16(gB + k0 + 32 + 16 * 1024, Bs + nb + 16 * 32);
        }
#pragma unroll
        for (int i = 0; i < 4; i++)
#pragma unroll
            for (int j = 0; j < 4; j++) acc[i][j] = MFMA_BF16(af[i], bfr[j], acc[i][j]);
    }
#pragma unroll
    for (int j = 0; j < 4; j++) {
        int n = n0 + wx * 64 + j * 16 + lr;
        int proj = n >> 10, rem = n & 1023, h = rem >> 6, e = rem & 63;
        if (proj == 2) {
            // V: write transposed [bh, e, s] with packed b64 stores down s (RNE pack!)
            float bb = bv[rem];
#pragma unroll
            for (int i = 0; i < 4; i++) {
                int m = m0 + wy * 64 + i * 16 + quad * 4;
                int batch = m >> 11, s = m & 2047;
                u32x2 pk;
                pk[0] = pack_bf16_rne(acc[i][j][0] + bb, acc[i][j][1] + bb);
                pk[1] = pack_bf16_rne(acc[i][j][2] + bb, acc[i][j][3] + bb);
                *(u32x2*)(VTo + (((size_t)batch * 16 + h) * 64 + e) * 2048 + s) = pk;
            }
        } else {
            const float* bias = (proj == 0) ? bq : bk;
            unsigned short* dst = (proj == 0) ? Qo : Ko;
            float bb = bias[rem];
            float scl = (proj == 0) ? QSCALE : 1.0f;
#pragma unroll
            for (int i = 0; i < 4; i++) {
#pragma unroll
                for (int r = 0; r < 4; r++) {
                    int m = m0 + wy * 64 + i * 16 + quad * 4 + r;
                    int batch = m >> 11, s = m & 2047;
                    dst[(((size_t)batch * 16 + h) * 2048 + s) * 64 + e] = f2bf((acc[i][j][r] + bb) * scl);
                }
            }
        }
    }
}

__global__ __launch_bounds__(256) void gemm_out_kernel(
    const unsigned short* __restrict__ A, const unsigned short* __restrict__ BT,
    const float* __restrict__ bo, float* __restrict__ out) {
    __shared__ unsigned short As[2 * 128 * 32];
    __shared__ unsigned short Bs[2 * 128 * 32];
    const int tid = threadIdx.x;
    const int m0 = blockIdx.y * 128, n0 = blockIdx.x * 128;
    const int w = tid >> 6, lane = tid & 63, lr = lane & 15, quad = lane >> 4;
    const int wy = w >> 1, wx = w & 1;
    f32x4 acc[4][4];
#pragma unroll
    for (int i = 0; i < 4; i++)
#pragma unroll
        for (int j = 0; j < 4; j++) acc[i][j] = (f32x4){0.f, 0.f, 0.f, 0.f};
    const int drow = lane >> 2;
    const int dchunk = (lane & 3) ^ (drow & 3);
    const unsigned short* gA = A + (size_t)(m0 + w * 32 + drow) * 1024 + dchunk * 8;
    const unsigned short* gB = BT + (size_t)(n0 + w * 32 + drow) * 1024 + dchunk * 8;
    const int swav = (w * 32) * 32;
    const int fcol = (quad ^ (lr & 3)) * 8;
    dma16(gA, As + swav);
    dma16(gA + 16 * 1024, As + swav + 16 * 32);
    dma16(gB, Bs + swav);
    dma16(gB + 16 * 1024, Bs + swav + 16 * 32);
    for (int k0 = 0; k0 < 1024; k0 += 32) {
        const int cur = (k0 >> 5) & 1;
        const unsigned short* cA = As + cur * 4096;
        const unsigned short* cB = Bs + cur * 4096;
        pipeline_barrier();
        bf16x8 af[4], bfr[4];
#pragma unroll
        for (int i = 0; i < 4; i++) af[i] = ldfrag(cA + (wy * 64 + i * 16 + lr) * 32 + fcol);
#pragma unroll
        for (int j = 0; j < 4; j++) bfr[j] = ldfrag(cB + (wx * 64 + j * 16 + lr) * 32 + fcol);
        if (k0 + 32 < 1024) {
            const int nb = (cur ^ 1) * 4096 + swav;
            dma16(gA + k0 + 32, As + nb);
            dma16(gA + k0 + 32 + 16 * 1024, As + nb + 16 * 32);
            dma16(gB + k0 + 32, Bs + nb);
            dma16(gB + k0 + 32 + 16 * 1024, Bs + nb + 16 * 32);
        }
#pragma unroll
        for (int i = 0; i < 4; i++)
#pragma unroll
            for (int j = 0; j < 4; j++) acc[i][j] = MFMA_BF16(af[i], bfr[j], acc[i][j]);
    }
#pragma unroll
    for (int j = 0; j < 4; j++) {
        int n = n0 + wx * 64 + j * 16 + lr;
        float bb = bo[n];
#pragma unroll
        for (int i = 0; i < 4; i++) {
#pragma unroll
            for (int r = 0; r < 4; r++) {
                int m = m0 + wy * 64 + i * 16 + quad * 4 + r;
                out[(size_t)m * 1024 + n] = acc[i][j][r] + bb;
            }
        }
    }
}

// ---------------- flash attention: 2-wave blocks, 4 blocks/CU, single-buffered K/V ----------------
// grid (bh=64 fastest, 16 q-tiles of 128) = 1024 blocks = 4 co-resident/CU (32 KB LDS);
// 4 independent barrier groups per CU cover each other's staging drains.
// K/V tiles: [64][64] u16, source-swizzled LDS(r,c)=global(r, c^(r&7)); frag chunk (kc*4+quad)^(lr&7).
// Ps: 128 rows x 64, XOR chunk swizzle addr = row*64 + ((chunk^(row&7))*8) + within  -> <=2-way everywhere.
__global__ __launch_bounds__(128, 2) void attn_fa_kernel(
    const unsigned short* __restrict__ Q, const unsigned short* __restrict__ K,
    const unsigned short* __restrict__ VT, unsigned short* __restrict__ Out) {
    __shared__ unsigned short Ks[64 * 64];
    __shared__ unsigned short Vs[64 * 64];
    __shared__ unsigned short Ps[128 * 64];  // rows W..W+63 private to wave w
    const int bh = blockIdx.x;
    const int q0 = blockIdx.y * 128;
    const int tid = threadIdx.x;
    const int w = tid >> 6, lane = tid & 63, lr = lane & 15, quad = lane >> 4;
    const int W = w * 64;
    const unsigned short* Qh = Q + (size_t)bh * 2048 * 64;
    const unsigned short* Kh = K + (size_t)bh * 2048 * 64;
    const unsigned short* Vh = VT + (size_t)bh * 64 * 2048;

    // DMA setup: wave w stages K/V rows w*32 .. w*32+31 (4 instrs of 8 rows each per operand)
    const int drow = lane >> 3;                 // 0..7
    const int dchunk = (lane & 7) ^ drow;       // source swizzle
    const unsigned short* gK = Kh + (size_t)(w * 32 + drow) * 64 + dchunk * 8;
    const unsigned short* gV = Vh + (size_t)(w * 32 + drow) * 2048 + dchunk * 8;
    unsigned short* sK = Ks + (w * 32) * 64;
    unsigned short* sV = Vs + (w * 32) * 64;

    {  // stage this block's 128 Q rows into Ps (thread = row), XOR chunk swizzle
        const unsigned short* g = Qh + (size_t)(q0 + tid) * 64;
        unsigned short* s = Ps + tid * 64;
        const int rx = tid & 7;
#pragma unroll
        for (int c = 0; c < 8; c++) *(u32x4*)(s + ((c ^ rx) * 8)) = *(const u32x4*)(g + c * 8);
    }
    __syncthreads();  // Ps rows are wave-private, but cheap and makes staging uniform
    bf16x8 qb[4][2];  // [q-16-group][kc]
#pragma unroll
    for (int nt = 0; nt < 4; nt++)
#pragma unroll
        for (int kc = 0; kc < 2; kc++)
            qb[nt][kc] = ldfrag(Ps + (W + nt * 16 + lr) * 64 + (((kc * 4 + quad) ^ (lr & 7)) * 8));

    f32x4 o[4][4];  // O[q-16-group][e-16-group]
#pragma unroll
    for (int i = 0; i < 4; i++)
#pragma unroll
        for (int j = 0; j < 4; j++) o[i][j] = (f32x4){0.f, 0.f, 0.f, 0.f};
    float lp[4] = {0.f, 0.f, 0.f, 0.f};

    for (int t0 = 0; t0 < 2048; t0 += 64) {
        __syncthreads();  // all waves done reading previous tile
        // stage tile t0 (4 K + 4 V dma16 per wave)
#pragma unroll
        for (int i = 0; i < 4; i++) {
            dma16(gK + (size_t)(t0 + i * 8) * 64, sK + i * 8 * 64);
            dma16(gV + (t0 + (size_t)i * 8 * 2048) - (size_t)0, sV + i * 8 * 64);
        }
        pipeline_barrier();  // each wave drains its DMA, then all waves see the tile

        // hoisted K/V fragment reads
        bf16x8 ka[2][4], vb[2][4];
#pragma unroll
        for (int kc = 0; kc < 2; kc++)
#pragma unroll
            for (int mt = 0; mt < 4; mt++) {
                int fc = ((kc * 4 + quad) ^ (lr & 7)) * 8;
                ka[kc][mt] = ldfrag(Ks + (mt * 16 + lr) * 64 + fc);
                vb[kc][mt] = ldfrag(Vs + (mt * 16 + lr) * 64 + fc);
            }

        // S^T = K·Q^T : C rows = t (mt), cols = q (nt)
        f32x4 sc[4][4];
#pragma unroll
        for (int mt = 0; mt < 4; mt++)
#pragma unroll
            for (int nt = 0; nt < 4; nt++) sc[mt][nt] = (f32x4){0.f, 0.f, 0.f, 0.f};
#pragma unroll
        for (int kc = 0; kc < 2; kc++)
#pragma unroll
            for (int mt = 0; mt < 4; mt++)
#pragma unroll
                for (int nt = 0; nt < 4; nt++)
                    sc[mt][nt] = MFMA_BF16(ka[kc][mt], qb[nt][kc], sc[mt][nt]);

        // p = exp2(s'); accumulate denominator; pack to swizzled bf16 rows of P[q][t]
#pragma unroll
        for (int nt = 0; nt < 4; nt++) {
            unsigned short* prow = Ps + (W + nt * 16 + lr) * 64 + (quad & 1) * 4;
            const int rx = lr & 7;
#pragma unroll
            for (int mt = 0; mt < 4; mt++) {
                float p0 = fast_exp2(sc[mt][nt][0]);
                float p1 = fast_exp2(sc[mt][nt][1]);
                float p2 = fast_exp2(sc[mt][nt][2]);
                float p3 = fast_exp2(sc[mt][nt][3]);
                lp[nt] += (p0 + p1) + (p2 + p3);
                u32x2 pk;
                pk[0] = pack_bf16(p0, p1);
                pk[1] = pack_bf16(p2, p3);
                // t-chunk = 2*mt + (quad>>1), swizzled by row&7
                *(u32x2*)(prow + (((2 * mt + (quad >> 1)) ^ rx) * 8)) = pk;
            }
        }

        // O += P·V  (pa from own-wave Ps rows; same-wave lgkm ordering suffices)
#pragma unroll
        for (int kc = 0; kc < 2; kc++) {
            bf16x8 pa[4];
#pragma unroll
            for (int nt = 0; nt < 4; nt++)
                pa[nt] = ldfrag(Ps + (W + nt * 16 + lr) * 64 + (((kc * 4 + quad) ^ (lr & 7)) * 8));
#pragma unroll
            for (int nt = 0; nt < 4; nt++)
#pragma unroll
                for (int et = 0; et < 4; et++)
                    o[nt][et] = MFMA_BF16(pa[nt], vb[kc][et], o[nt][et]);
        }
    }

    // final denominator: reduce across the 4 quads
#pragma unroll
    for (int nt = 0; nt < 4; nt++) {
        float l = lp[nt];
        l += __shfl_xor(l, 16, 64);
        l += __shfl_xor(l, 32, 64);
        lp[nt] = l;
    }

    // normalize + write attn [B,S,H*E] bf16
    const int h = bh & 15, b = bh >> 4;
#pragma unroll
    for (int nt = 0; nt < 4; nt++) {
#pragma unroll
        for (int r = 0; r < 4; r++) {
            float l = __shfl(lp[nt], quad * 4 + r, 16);
            float inv = 1.0f / l;
            int s = q0 + W + nt * 16 + quad * 4 + r;
#pragma unroll
            for (int et = 0; et < 4; et++) {
                int col = h * 64 + et * 16 + lr;
                Out[((size_t)(b * 2048 + s)) * 1024 + col] = f2bf(o[nt][et][r] * inv);
            }
        }
    }
}

// ---------------- launch ----------------

extern "C" void kernel_launch(void* const* d_in, const int* in_sizes, int n_in,
                              void* d_out, int out_size, void* d_ws, size_t ws_size,
                              hipStream_t stream) {
    const float* x  = (const float*)d_in[0];
    const float* Wq = (const float*)d_in[1];
    const float* bq = (const float*)d_in[2];
    const float* Wk = (const float*)d_in[3];
    const float* bk = (const float*)d_in[4];
    const float* Wv = (const float*)d_in[5];
    const float* bv = (const float*)d_in[6];
    const float* Wo = (const float*)d_in[7];
    const float* bo = (const float*)d_in[8];
    float* out = (float*)d_out;

    char* ws = (char*)d_ws;
    unsigned short* xb    = (unsigned short*)(ws);              // 16 MiB; reused as attn buffer
    unsigned short* WqkvT = (unsigned short*)(ws + 16777216);   // 6 MiB
    unsigned short* WoT   = (unsigned short*)(ws + 23068672);   // 2 MiB
    unsigned short* Qb    = (unsigned short*)(ws + 25165824);   // 16 MiB
    unsigned short* Kb    = (unsigned short*)(ws + 41943040);   // 16 MiB
    unsigned short* VTb   = (unsigned short*)(ws + 58720256);   // 16 MiB (total 72 MiB)
    unsigned short* attn  = xb;  // xb is dead after gemm_qkv

    cvt_x_kernel<<<dim3(4096), dim3(256), 0, stream>>>(x, xb);
    cvt_wqkvT_kernel<<<dim3(12, 128), dim3(256), 0, stream>>>(Wq, Wk, Wv, WqkvT);
    cvt_woT_kernel<<<dim3(4, 128), dim3(256), 0, stream>>>(Wo, WoT);
    gemm_qkv_kernel<<<dim3(24, 64), dim3(256), 0, stream>>>(xb, WqkvT, bq, bk, bv, Qb, Kb, VTb);
    attn_fa_kernel<<<dim3(64, 16), dim3(128), 0, stream>>>(Qb, Kb, VTb, attn);
    gemm_out_kernel<<<dim3(8, 64), dim3(256), 0, stream>>>(attn, WoT, bo, out);
}